// Round 18
// baseline (182.858 us; speedup 1.0000x reference)
//
#include <hip/hip_runtime.h>

#define H 12
#define T 2048
#define HD 64
#define CEMB 768
#define M1 8192   // B*T
#define N1 2304   // 3*C
#define K1 768

typedef __attribute__((ext_vector_type(8))) short bf8;
typedef __attribute__((ext_vector_type(4))) float f4;
typedef __attribute__((ext_vector_type(16))) float f16v;
typedef __attribute__((ext_vector_type(4))) int i4;

__device__ __forceinline__ unsigned short f2bf(float f){
  union { float f; unsigned u; } v; v.f = f;
  unsigned r = v.u + 0x7FFFu + ((v.u >> 16) & 1u);
  return (unsigned short)(r >> 16);
}

__device__ __forceinline__ int cvtpk(float a, float b){
  int r;
  asm("v_cvt_pk_bf16_f32 %0, %1, %2" : "=v"(r) : "v"(a), "v"(b));
  return r;
}

// async global->LDS, 16B per lane; dest = wave-uniform base + lane*16
__device__ __forceinline__ void gload16(const unsigned short* g, unsigned short* l){
  __builtin_amdgcn_global_load_lds((const __attribute__((address_space(1))) void*)g,
                                   (__attribute__((address_space(3))) void*)l, 16, 0, 0);
}

// ---- fused f32->bf16 conversion over x, W_attn, W_o (one launch, 3 ranges) ----
__global__ __launch_bounds__(256) void cvt_all(const float* __restrict__ x,
                                               const float* __restrict__ wa,
                                               const float* __restrict__ wo,
                                               unsigned short* __restrict__ xb,
                                               unsigned short* __restrict__ wab,
                                               unsigned short* __restrict__ wob){
  const int n4x = M1 * K1 / 4, n4a = N1 * K1 / 4, n4o = CEMB * CEMB / 4;
  int i = blockIdx.x * blockDim.x + threadIdx.x;
  const float* in; unsigned short* out; int j;
  if (i < n4x){ in = x; out = xb; j = i; }
  else if (i < n4x + n4a){ in = wa; out = wab; j = i - n4x; }
  else if (i < n4x + n4a + n4o){ in = wo; out = wob; j = i - n4x - n4a; }
  else return;
  float4 v = ((const float4*)in)[j];
  int2 o;
  o.x = cvtpk(v.x, v.y);
  o.y = cvtpk(v.z, v.w);
  ((int2*)out)[j] = o;
}

// ---- QKV projection (m97-style). Q pre-scaled by 0.125*log2(e). ----
// V is written DIRECTLY in the transposed + kv-quad-permuted layout the attn
// kernel consumes (Vt[bh][d][perm(t)]), fusing the old transpose_v kernel.
__global__ __launch_bounds__(256) void gemm_qkv(const unsigned short* __restrict__ A,
                                                const unsigned short* __restrict__ Wb,
                                                const float* __restrict__ bias,
                                                unsigned short* __restrict__ Qb,
                                                unsigned short* __restrict__ Kb,
                                                unsigned short* __restrict__ Vt){
  __shared__ __align__(16) unsigned short As[128][64];
  __shared__ __align__(16) unsigned short Bs[128][64];
  int Lid = blockIdx.x + gridDim.x * blockIdx.y;      // 18*64 = 1152 = 8*144
  int L2 = (Lid & 7) * 144 + (Lid >> 3);
  const int m0 = (L2 / 18) * 128, n0 = (L2 % 18) * 128;
  const int tid = threadIdx.x, w = tid >> 6, lane = tid & 63;
  const int wm = (w >> 1) * 64, wn = (w & 1) * 64;
  const int l15 = lane & 15, g = lane >> 4;
  const int srow = lane >> 3;
  const int scol = ((lane & 7) ^ srow) * 8;
  f4 acc[4][4] = {};
  for (int k0 = 0; k0 < K1; k0 += 64){
    #pragma unroll
    for (int i = 0; i < 4; ++i){
      int rb = i * 32 + w * 8;
      gload16(&A [(size_t)(m0 + rb + srow) * K1 + k0 + scol], &As[rb][0]);
      gload16(&Wb[(size_t)(n0 + rb + srow) * K1 + k0 + scol], &Bs[rb][0]);
    }
    __syncthreads();
    #pragma unroll
    for (int kq = 0; kq < 2; ++kq){
      bf8 a[4], b[4];
      #pragma unroll
      for (int i = 0; i < 4; ++i){
        int row = wm + i * 16 + l15;
        a[i] = *(const bf8*)&As[row][(((kq << 2) + g) ^ (row & 7)) * 8];
      }
      #pragma unroll
      for (int j = 0; j < 4; ++j){
        int row = wn + j * 16 + l15;
        b[j] = *(const bf8*)&Bs[row][(((kq << 2) + g) ^ (row & 7)) * 8];
      }
      #pragma unroll
      for (int i = 0; i < 4; ++i)
        #pragma unroll
        for (int j = 0; j < 4; ++j)
          acc[i][j] = __builtin_amdgcn_mfma_f32_16x16x32_bf16(a[i], b[j], acc[i][j], 0, 0, 0);
    }
    __syncthreads();
  }
  const int qd = ((g & 1) << 1) | (g >> 1);   // kv-quad permute: 1<->2 swap
  #pragma unroll
  for (int j = 0; j < 4; ++j){
    int ncol = n0 + wn + j * 16 + l15;
    float bv = bias[ncol];
    int which = ncol / CEMB;                  // uniform within the 16-col group
    int cc = ncol - which * CEMB;
    int h = cc >> 6, d = cc & 63;
    if (which == 2){
      #pragma unroll
      for (int i = 0; i < 4; ++i){
        int m = m0 + wm + i * 16;             // aligned quad-group base
        int b_ = m >> 11, tb = (m & 2047) + qd * 4;
        ushort4 pk;
        pk.x = f2bf(acc[i][j][0] + bv);
        pk.y = f2bf(acc[i][j][1] + bv);
        pk.z = f2bf(acc[i][j][2] + bv);
        pk.w = f2bf(acc[i][j][3] + bv);
        *(ushort4*)&Vt[((size_t)(b_ * H + h) * HD + d) * T + tb] = pk;
      }
    } else {
      #pragma unroll
      for (int i = 0; i < 4; ++i){
        #pragma unroll
        for (int r = 0; r < 4; ++r){
          int m = m0 + wm + i * 16 + g * 4 + r;
          int b_ = m >> 11, t = m & 2047;
          size_t idx = ((size_t)(b_ * H + h) * T + t) * HD + d;
          float v = acc[i][j][r] + bv;
          if (which == 0) Qb[idx] = f2bf(v * 0.18033688f);  // 0.125 * log2(e)
          else            Kb[idx] = f2bf(v);
        }
      }
    }
  }
}

// ---- Flash causal attention v21: KVBLK=64 (parameter change ONLY; the
// proven mechanism -- 1-wave block, dynamic [2] double buffer, gload16,
// counted vmcnt -- is untouched) ----
// R14 measured per-tile cost ~3300 cyc invariant to prefetch depth (fixed
// drain/queue cost per staged batch); compute is only ~600 cyc/tile. KVBLK=64
// pays the fixed cost once per TWO old tiles: 16 loads + 20 MFMAs per big
// tile. Second K/V half read at rows 32+q31 (same XOR key, 32 == 0 mod 8);
// s1 mirrors s0; PV slices ks=2,3 consume s1; one diagonal mask covers both
// halves (even-qidx overshoot rows are in-bounds and fully masked).
// LDS 32 KiB -> 5 blocks/CU (measured avg residency was 5.76). Numerics,
// swizzles, epilogue, grid, LPT order unchanged from the 9/9-passing kernel.
__global__ __launch_bounds__(64) void attn(const unsigned short* __restrict__ Qb,
                                           const unsigned short* __restrict__ Kb,
                                           const unsigned short* __restrict__ Vt,
                                           unsigned short* __restrict__ Yb){
  __shared__ __align__(16) unsigned short Ks[2][64][64];
  __shared__ __align__(16) unsigned short Vs[2][64][64];
  const int bh = blockIdx.x;                 // 48 % 8 == 0 -> bh pinned to one XCD
  const int qidx = 63 - (int)blockIdx.y;     // LPT: heavy q-tiles dispatched first
  const int lane = threadIdx.x;
  const int q31 = lane & 31, hi = lane >> 5;
  const int q0 = qidx * 32;
  const unsigned short* Qp = Qb + (size_t)bh * T * HD;
  const unsigned short* Kp = Kb + (size_t)bh * T * HD;
  const unsigned short* Vp = Vt + (size_t)bh * HD * T;
  const int b_ = bh / H, h = bh % H;

  // staging lane constants: K and V rows are both 64 shorts (128 B) now,
  // so both use the 8-rows-per-call pattern with key (row & 7).
  const int krow = lane >> 3;                         // 0..7 within 8-row slab
  const int kcs  = ((lane & 7) ^ krow) * 8;           // chunk ^ (row&7)

  // Q fragments (B-operand): lane holds Q[q0+q31][ds*16 + hi*8 .. +8]
  bf8 qf[4];
  #pragma unroll
  for (int ds = 0; ds < 4; ++ds)
    qf[ds] = *(const bf8*)&Qp[(q0 + q31) * HD + ds * 16 + hi * 8];

  // all-ones bf16 B operand for the row-sum MFMA
  bf8 ones;
  #pragma unroll
  for (int j = 0; j < 8; ++j) ones[j] = (short)0x3F80;

  f16v o0 = {}, o1 = {}, ol = {};
  float m_i = -1e30f;
  const int ntw = (qidx >> 1) + 1;           // 64-wide kv tiles

  // prologue: stage tile 0 into buf 0 (8 K-calls + 8 V-calls = 16 loads)
  #pragma unroll
  for (int it = 0; it < 8; ++it)
    gload16(&Kp[(size_t)(it * 8 + krow) * HD + kcs], &Ks[0][it * 8][0]);
  #pragma unroll
  for (int it = 0; it < 8; ++it)
    gload16(&Vp[(size_t)(it * 8 + krow) * T + kcs], &Vs[0][it * 8][0]);

  for (int t = 0; t < ntw; ++t){
    const int cur = t & 1;
    const int kv0 = t * 64;
    if (t + 1 < ntw){     // stage next tile into other buffer, then counted wait
      const int nkv = kv0 + 64;
      #pragma unroll
      for (int it = 0; it < 8; ++it)
        gload16(&Kp[(size_t)(nkv + it * 8 + krow) * HD + kcs], &Ks[cur ^ 1][it * 8][0]);
      #pragma unroll
      for (int it = 0; it < 8; ++it)
        gload16(&Vp[(size_t)(it * 8 + krow) * T + nkv + kcs], &Vs[cur ^ 1][it * 8][0]);
      asm volatile("s_waitcnt vmcnt(16)" ::: "memory");   // drain tile t only
    } else {
      asm volatile("s_waitcnt vmcnt(0)" ::: "memory");
    }
    __builtin_amdgcn_sched_barrier(0);

    // ---- QK^T (swapped), both kv halves: s0 = kv[0..32), s1 = kv[32..64)
    f16v s0 = {}, s1 = {};
    __builtin_amdgcn_s_setprio(1);
    #pragma unroll
    for (int ds = 0; ds < 4; ++ds){
      bf8 k0 = *(const bf8*)&Ks[cur][q31]     [(((2 * ds + hi)) ^ (q31 & 7)) * 8];
      bf8 k1 = *(const bf8*)&Ks[cur][32 + q31][(((2 * ds + hi)) ^ (q31 & 7)) * 8];
      s0 = __builtin_amdgcn_mfma_f32_32x32x16_bf16(k0, qf[ds], s0, 0, 0, 0);
      s1 = __builtin_amdgcn_mfma_f32_32x32x16_bf16(k1, qf[ds], s1, 0, 0, 0);
    }
    __builtin_amdgcn_s_setprio(0);
    if (t == ntw - 1){    // diagonal tile: causal mask over both halves
      #pragma unroll
      for (int r = 0; r < 16; ++r){
        int kvr = kv0 + (r & 3) + 8 * (r >> 2) + 4 * hi;
        if (kvr > q0 + q31)      s0[r] = -1e30f;
        if (kvr + 32 > q0 + q31) s1[r] = -1e30f;
      }
    }
    // ---- row max: v_max3 triplet trees over both halves
    float a0 = fmaxf(fmaxf(s0[0], s0[1]), s0[2]);
    float a1 = fmaxf(fmaxf(s0[3], s0[4]), s0[5]);
    float a2 = fmaxf(fmaxf(s0[6], s0[7]), s0[8]);
    float a3 = fmaxf(fmaxf(s0[9], s0[10]), s0[11]);
    float a4 = fmaxf(fmaxf(s0[12], s0[13]), s0[14]);
    float mxa = fmaxf(fmaxf(fmaxf(a0, a1), a2), fmaxf(fmaxf(a3, a4), s0[15]));
    float b0 = fmaxf(fmaxf(s1[0], s1[1]), s1[2]);
    float b1 = fmaxf(fmaxf(s1[3], s1[4]), s1[5]);
    float b2 = fmaxf(fmaxf(s1[6], s1[7]), s1[8]);
    float b3 = fmaxf(fmaxf(s1[9], s1[10]), s1[11]);
    float b4 = fmaxf(fmaxf(s1[12], s1[13]), s1[14]);
    float mxb = fmaxf(fmaxf(fmaxf(b0, b1), b2), fmaxf(fmaxf(b3, b4), s1[15]));
    float mx = fmaxf(mxa, mxb);
    mx = fmaxf(mx, __shfl_xor(mx, 32));
    // ---- defer-max: rescale only when max grew by > 8 (log2 domain);
    //      scale redistributed via shfl (row f(r,hi) held by lane q31==row)
    if (__any(mx > m_i + 8.f)){
      float mn = fmaxf(m_i, mx);
      float sc_ = __builtin_exp2f(m_i - mn);
      #pragma unroll
      for (int r = 0; r < 16; ++r){
        float s = __shfl(sc_, (r & 3) + 8 * (r >> 2) + 4 * hi);
        o0[r] *= s; o1[r] *= s; ol[r] *= s;
      }
      m_i = mn;
    }
    // ---- p = exp2(s - m) in place, both halves
    #pragma unroll
    for (int r = 0; r < 16; ++r) s0[r] = __builtin_exp2f(s0[r] - m_i);
    #pragma unroll
    for (int r = 0; r < 16; ++r) s1[r] = __builtin_exp2f(s1[r] - m_i);
    // ---- PV + row-sum over 4 k-slices: ks 0,1 from s0; ks 2,3 from s1
    union { i4 i; bf8 h; } pa;
    __builtin_amdgcn_s_setprio(1);
    #pragma unroll
    for (int ks = 0; ks < 4; ++ks){
      const int off = (ks & 1) * 8;
      if (ks < 2)
        pa.i = (i4){ cvtpk(s0[off], s0[off+1]), cvtpk(s0[off+2], s0[off+3]),
                     cvtpk(s0[off+4], s0[off+5]), cvtpk(s0[off+6], s0[off+7]) };
      else
        pa.i = (i4){ cvtpk(s1[off], s1[off+1]), cvtpk(s1[off+2], s1[off+3]),
                     cvtpk(s1[off+4], s1[off+5]), cvtpk(s1[off+6], s1[off+7]) };
      bf8 v0 = *(const bf8*)&Vs[cur][q31]     [((2 * ks + hi) ^ (q31 & 7)) * 8];
      bf8 v1 = *(const bf8*)&Vs[cur][32 + q31][((2 * ks + hi) ^ (q31 & 7)) * 8];
      o0 = __builtin_amdgcn_mfma_f32_32x32x16_bf16(pa.h, v0, o0, 0, 0, 0);
      o1 = __builtin_amdgcn_mfma_f32_32x32x16_bf16(pa.h, v1, o1, 0, 0, 0);
      ol = __builtin_amdgcn_mfma_f32_32x32x16_bf16(pa.h, ones, ol, 0, 0, 0);
    }
    __builtin_amdgcn_s_setprio(0);
  }

  // ---- epilogue: per-register exact 1/l, store Y (bf16); no LDS, no cross-lane
  #pragma unroll
  for (int r = 0; r < 16; ++r){
    int qrow = q0 + (r & 3) + 8 * (r >> 2) + 4 * hi;
    float inv = 1.0f / ol[r];
    size_t base = ((size_t)b_ * T + qrow) * CEMB + h * HD;
    Yb[base + q31]      = f2bf(o0[r] * inv);
    Yb[base + 32 + q31] = f2bf(o1[r] * inv);
  }
}

// ---- Output projection (m97 structure), fp32 out ----
__global__ __launch_bounds__(256) void gemm_out(const unsigned short* __restrict__ A,
                                                const unsigned short* __restrict__ Wb,
                                                const float* __restrict__ bias,
                                                float* __restrict__ out){
  __shared__ __align__(16) unsigned short As[128][64];
  __shared__ __align__(16) unsigned short Bs[128][64];
  int Lid = blockIdx.x + gridDim.x * blockIdx.y;      // 6*64 = 384 = 8*48
  int L2 = (Lid & 7) * 48 + (Lid >> 3);
  const int m0 = (L2 / 6) * 128, n0 = (L2 % 6) * 128;
  const int tid = threadIdx.x, w = tid >> 6, lane = tid & 63;
  const int wm = (w >> 1) * 64, wn = (w & 1) * 64;
  const int l15 = lane & 15, g = lane >> 4;
  const int srow = lane >> 3;
  const int scol = ((lane & 7) ^ srow) * 8;
  f4 acc[4][4] = {};
  for (int k0 = 0; k0 < CEMB; k0 += 64){
    #pragma unroll
    for (int i = 0; i < 4; ++i){
      int rb = i * 32 + w * 8;
      gload16(&A [(size_t)(m0 + rb + srow) * CEMB + k0 + scol], &As[rb][0]);
      gload16(&Wb[(size_t)(n0 + rb + srow) * CEMB + k0 + scol], &Bs[rb][0]);
    }
    __syncthreads();
    #pragma unroll
    for (int kq = 0; kq < 2; ++kq){
      bf8 a[4], b[4];
      #pragma unroll
      for (int i = 0; i < 4; ++i){
        int row = wm + i * 16 + l15;
        a[i] = *(const bf8*)&As[row][(((kq << 2) + g) ^ (row & 7)) * 8];
      }
      #pragma unroll
      for (int j = 0; j < 4; ++j){
        int row = wn + j * 16 + l15;
        b[j] = *(const bf8*)&Bs[row][(((kq << 2) + g) ^ (row & 7)) * 8];
      }
      #pragma unroll
      for (int i = 0; i < 4; ++i)
        #pragma unroll
        for (int j = 0; j < 4; ++j)
          acc[i][j] = __builtin_amdgcn_mfma_f32_16x16x32_bf16(a[i], b[j], acc[i][j], 0, 0, 0);
    }
    __syncthreads();
  }
  #pragma unroll
  for (int j = 0; j < 4; ++j){
    int ncol = n0 + wn + j * 16 + l15;
    float bv = bias[ncol];
    #pragma unroll
    for (int i = 0; i < 4; ++i){
      #pragma unroll
      for (int r = 0; r < 4; ++r){
        int m = m0 + wm + i * 16 + g * 4 + r;
        out[(size_t)m * CEMB + ncol] = acc[i][j][r] + bv;
      }
    }
  }
}

extern "C" void kernel_launch(void* const* d_in, const int* in_sizes, int n_in,
                              void* d_out, int out_size, void* d_ws, size_t ws_size,
                              hipStream_t stream){
  const float* x      = (const float*)d_in[0];
  const float* W_attn = (const float*)d_in[1];
  const float* b_attn = (const float*)d_in[2];
  const float* W_o    = (const float*)d_in[3];
  const float* b_o    = (const float*)d_in[4];
  float* out = (float*)d_out;

  char* ws = (char*)d_ws;
  const size_t SZ_T  = (size_t)48 * T * HD * 2;   // 12.58 MB (== X size)
  const size_t SZ_WA = (size_t)N1 * K1 * 2;
  const size_t SZ_WO = (size_t)CEMB * CEMB * 2;
  unsigned short* Xb = (unsigned short*)(ws);
  unsigned short* Wa = (unsigned short*)(ws + SZ_T);
  unsigned short* Wo = (unsigned short*)(ws + SZ_T + SZ_WA);
  unsigned short* Qb = (unsigned short*)(ws + SZ_T + SZ_WA + SZ_WO);
  unsigned short* Kb = (unsigned short*)(ws + SZ_T + SZ_WA + SZ_WO + SZ_T);
  unsigned short* Vt = (unsigned short*)(ws + SZ_T + SZ_WA + SZ_WO + 2 * SZ_T);
  unsigned short* Yb = Xb;   // Xb dead after gemm_qkv; attn writes Y here

  const int n4tot = (M1 * K1 + N1 * K1 + CEMB * CEMB) / 4;
  cvt_all<<<(n4tot + 255) / 256, 256, 0, stream>>>(x, W_attn, W_o, Xb, Wa, Wo);

  gemm_qkv<<<dim3(N1 / 128, M1 / 128), 256, 0, stream>>>(Xb, Wa, b_attn, Qb, Kb, Vt);
  attn<<<dim3(48, 64), 64, 0, stream>>>(Qb, Kb, Vt, Yb);
  gemm_out<<<dim3(CEMB / 128, M1 / 128), 256, 0, stream>>>(Yb, Wo, b_o, out);
}

// Round 19
// 159.035 us; speedup vs baseline: 1.1498x; 1.1498x over previous
//
#include <hip/hip_runtime.h>

#define H 12
#define T 2048
#define HD 64
#define CEMB 768
#define M1 8192   // B*T
#define N1 2304   // 3*C
#define K1 768

typedef __attribute__((ext_vector_type(8))) short bf8;
typedef __attribute__((ext_vector_type(4))) float f4;
typedef __attribute__((ext_vector_type(16))) float f16v;
typedef __attribute__((ext_vector_type(4))) int i4;

__device__ __forceinline__ unsigned short f2bf(float f){
  union { float f; unsigned u; } v; v.f = f;
  unsigned r = v.u + 0x7FFFu + ((v.u >> 16) & 1u);
  return (unsigned short)(r >> 16);
}

__device__ __forceinline__ int cvtpk(float a, float b){
  int r;
  asm("v_cvt_pk_bf16_f32 %0, %1, %2" : "=v"(r) : "v"(a), "v"(b));
  return r;
}

// async global->LDS, 16B per lane; dest = wave-uniform base + lane*16
__device__ __forceinline__ void gload16(const unsigned short* g, unsigned short* l){
  __builtin_amdgcn_global_load_lds((const __attribute__((address_space(1))) void*)g,
                                   (__attribute__((address_space(3))) void*)l, 16, 0, 0);
}

// ---- fused f32->bf16 conversion over x, W_attn, W_o (one launch, 3 ranges) ----
__global__ __launch_bounds__(256) void cvt_all(const float* __restrict__ x,
                                               const float* __restrict__ wa,
                                               const float* __restrict__ wo,
                                               unsigned short* __restrict__ xb,
                                               unsigned short* __restrict__ wab,
                                               unsigned short* __restrict__ wob){
  const int n4x = M1 * K1 / 4, n4a = N1 * K1 / 4, n4o = CEMB * CEMB / 4;
  int i = blockIdx.x * blockDim.x + threadIdx.x;
  const float* in; unsigned short* out; int j;
  if (i < n4x){ in = x; out = xb; j = i; }
  else if (i < n4x + n4a){ in = wa; out = wab; j = i - n4x; }
  else if (i < n4x + n4a + n4o){ in = wo; out = wob; j = i - n4x - n4a; }
  else return;
  float4 v = ((const float4*)in)[j];
  int2 o;
  o.x = cvtpk(v.x, v.y);
  o.y = cvtpk(v.z, v.w);
  ((int2*)out)[j] = o;
}

// ---- QKV projection (m97-style). Q pre-scaled by 0.125*log2(e). ----
// V is written DIRECTLY in the transposed + kv-quad-permuted layout the attn
// kernel consumes (Vt[bh][d][perm(t)]), fusing the old transpose_v kernel.
__global__ __launch_bounds__(256) void gemm_qkv(const unsigned short* __restrict__ A,
                                                const unsigned short* __restrict__ Wb,
                                                const float* __restrict__ bias,
                                                unsigned short* __restrict__ Qb,
                                                unsigned short* __restrict__ Kb,
                                                unsigned short* __restrict__ Vt){
  __shared__ __align__(16) unsigned short As[128][64];
  __shared__ __align__(16) unsigned short Bs[128][64];
  int Lid = blockIdx.x + gridDim.x * blockIdx.y;      // 18*64 = 1152 = 8*144
  int L2 = (Lid & 7) * 144 + (Lid >> 3);
  const int m0 = (L2 / 18) * 128, n0 = (L2 % 18) * 128;
  const int tid = threadIdx.x, w = tid >> 6, lane = tid & 63;
  const int wm = (w >> 1) * 64, wn = (w & 1) * 64;
  const int l15 = lane & 15, g = lane >> 4;
  const int srow = lane >> 3;
  const int scol = ((lane & 7) ^ srow) * 8;
  f4 acc[4][4] = {};
  for (int k0 = 0; k0 < K1; k0 += 64){
    #pragma unroll
    for (int i = 0; i < 4; ++i){
      int rb = i * 32 + w * 8;
      gload16(&A [(size_t)(m0 + rb + srow) * K1 + k0 + scol], &As[rb][0]);
      gload16(&Wb[(size_t)(n0 + rb + srow) * K1 + k0 + scol], &Bs[rb][0]);
    }
    __syncthreads();
    #pragma unroll
    for (int kq = 0; kq < 2; ++kq){
      bf8 a[4], b[4];
      #pragma unroll
      for (int i = 0; i < 4; ++i){
        int row = wm + i * 16 + l15;
        a[i] = *(const bf8*)&As[row][(((kq << 2) + g) ^ (row & 7)) * 8];
      }
      #pragma unroll
      for (int j = 0; j < 4; ++j){
        int row = wn + j * 16 + l15;
        b[j] = *(const bf8*)&Bs[row][(((kq << 2) + g) ^ (row & 7)) * 8];
      }
      #pragma unroll
      for (int i = 0; i < 4; ++i)
        #pragma unroll
        for (int j = 0; j < 4; ++j)
          acc[i][j] = __builtin_amdgcn_mfma_f32_16x16x32_bf16(a[i], b[j], acc[i][j], 0, 0, 0);
    }
    __syncthreads();
  }
  const int qd = ((g & 1) << 1) | (g >> 1);   // kv-quad permute: 1<->2 swap
  #pragma unroll
  for (int j = 0; j < 4; ++j){
    int ncol = n0 + wn + j * 16 + l15;
    float bv = bias[ncol];
    int which = ncol / CEMB;                  // uniform within the 16-col group
    int cc = ncol - which * CEMB;
    int h = cc >> 6, d = cc & 63;
    if (which == 2){
      #pragma unroll
      for (int i = 0; i < 4; ++i){
        int m = m0 + wm + i * 16;             // aligned quad-group base
        int b_ = m >> 11, tb = (m & 2047) + qd * 4;
        ushort4 pk;
        pk.x = f2bf(acc[i][j][0] + bv);
        pk.y = f2bf(acc[i][j][1] + bv);
        pk.z = f2bf(acc[i][j][2] + bv);
        pk.w = f2bf(acc[i][j][3] + bv);
        *(ushort4*)&Vt[((size_t)(b_ * H + h) * HD + d) * T + tb] = pk;
      }
    } else {
      #pragma unroll
      for (int i = 0; i < 4; ++i){
        #pragma unroll
        for (int r = 0; r < 4; ++r){
          int m = m0 + wm + i * 16 + g * 4 + r;
          int b_ = m >> 11, t = m & 2047;
          size_t idx = ((size_t)(b_ * H + h) * T + t) * HD + d;
          float v = acc[i][j][r] + bv;
          if (which == 0) Qb[idx] = f2bf(v * 0.18033688f);  // 0.125 * log2(e)
          else            Kb[idx] = f2bf(v);
        }
      }
    }
  }
}

// ---- Flash causal attention (the 9/9-passing kernel, byte-identical) ----
// FINAL SESSION LEDGER (11 attn experiments):
//  * staging-mechanism changes: 6/6 FAIL (cross-wave sharing x3, reg-staging,
//    static A/B buffers, single buffer). The WAR hazard between ds_read and a
//    later global_load_lds write to the same LDS region is closed ONLY by the
//    one-full-tile slack of this exact dynamically-indexed double buffer.
//  * VALU micro-cuts: neutral 3x. 2-stream ILP: regression (VGPR cliff @128).
//  * prefetch depth 2: regression (zero latency benefit; time ~ 1/residency).
//  * KVBLK=64: regression (LDS 32K -> 5 blocks/CU; 2x bank conflicts).
// Occupancy-vs-LDS curve measured: 16KB@10 = 93us (optimum), 24KB@6 = 105us,
// 32KB@5 = 121us. Throughput = residency / fixed-per-tile-latency; this
// config maximizes residency. DO NOT MODIFY.
__global__ __launch_bounds__(64) void attn(const unsigned short* __restrict__ Qb,
                                           const unsigned short* __restrict__ Kb,
                                           const unsigned short* __restrict__ Vt,
                                           unsigned short* __restrict__ Yb){
  __shared__ __align__(16) unsigned short Ks[2][32][64];
  __shared__ __align__(16) unsigned short Vs[2][64][32];
  const int bh = blockIdx.x;                 // 48 % 8 == 0 -> bh pinned to one XCD
  const int qidx = 63 - (int)blockIdx.y;     // LPT: heavy q-tiles dispatched first
  const int lane = threadIdx.x;
  const int q31 = lane & 31, hi = lane >> 5;
  const int q0 = qidx * 32;
  const unsigned short* Qp = Qb + (size_t)bh * T * HD;
  const unsigned short* Kp = Kb + (size_t)bh * T * HD;
  const unsigned short* Vp = Vt + (size_t)bh * HD * T;
  const int b_ = bh / H, h = bh % H;

  // staging lane constants (pre-swizzled source chunks; LDS dest is linear)
  const int krow = lane >> 3;                         // 0..7 within 8-row slab
  const int kcs  = ((lane & 7) ^ krow) * 8;           // K: chunk ^ (row&7)
  const int vrow = lane >> 2;                         // 0..15 within 16-row slab
  const int vcs  = ((lane & 3) ^ ((lane >> 4) & 3)) * 8;  // V: chunk ^ ((d>>2)&3)

  // Q fragments (B-operand): lane holds Q[q0+q31][ds*16 + hi*8 .. +8]
  bf8 qf[4];
  #pragma unroll
  for (int ds = 0; ds < 4; ++ds)
    qf[ds] = *(const bf8*)&Qp[(q0 + q31) * HD + ds * 16 + hi * 8];

  // all-ones bf16 B operand for the row-sum MFMA
  bf8 ones;
  #pragma unroll
  for (int j = 0; j < 8; ++j) ones[j] = (short)0x3F80;

  f16v o0 = {}, o1 = {}, ol = {};
  float m_i = -1e30f;
  const int ntw = qidx + 1;

  // prologue: stage tile 0 into buf 0
  #pragma unroll
  for (int it = 0; it < 4; ++it)
    gload16(&Kp[(size_t)(it * 8 + krow) * HD + kcs], &Ks[0][it * 8][0]);
  #pragma unroll
  for (int it = 0; it < 4; ++it)
    gload16(&Vp[(size_t)(it * 16 + vrow) * T + vcs], &Vs[0][it * 16][0]);

  #pragma unroll 2
  for (int t = 0; t < ntw; ++t){
    const int cur = t & 1;
    const int kv0 = t * 32;
    if (t + 1 < ntw){     // stage next tile into other buffer, then counted wait
      const int nkv = kv0 + 32;
      #pragma unroll
      for (int it = 0; it < 4; ++it)
        gload16(&Kp[(size_t)(nkv + it * 8 + krow) * HD + kcs], &Ks[cur ^ 1][it * 8][0]);
      #pragma unroll
      for (int it = 0; it < 4; ++it)
        gload16(&Vp[(size_t)(it * 16 + vrow) * T + nkv + vcs], &Vs[cur ^ 1][it * 16][0]);
      asm volatile("s_waitcnt vmcnt(12)" ::: "memory");   // drain tile t only
    } else {
      asm volatile("s_waitcnt vmcnt(0)" ::: "memory");
    }
    __builtin_amdgcn_sched_barrier(0);

    // ---- QK^T (swapped): s[kv][q]; K from LDS (XOR-swizzled read)
    f16v s0 = {};
    __builtin_amdgcn_s_setprio(1);
    #pragma unroll
    for (int ds = 0; ds < 4; ++ds){
      bf8 k0 = *(const bf8*)&Ks[cur][q31][(((2 * ds + hi)) ^ (q31 & 7)) * 8];
      s0 = __builtin_amdgcn_mfma_f32_32x32x16_bf16(k0, qf[ds], s0, 0, 0, 0);
    }
    __builtin_amdgcn_s_setprio(0);
    if (t == ntw - 1){    // diagonal tile: causal mask
      #pragma unroll
      for (int r = 0; r < 16; ++r){
        int kvr = kv0 + (r & 3) + 8 * (r >> 2) + 4 * hi;
        if (kvr > q0 + q31) s0[r] = -1e30f;
      }
    }
    // ---- row max: v_max3 triplet tree (identical result, ~7 insts vs ~32)
    float a0 = fmaxf(fmaxf(s0[0], s0[1]), s0[2]);
    float a1 = fmaxf(fmaxf(s0[3], s0[4]), s0[5]);
    float a2 = fmaxf(fmaxf(s0[6], s0[7]), s0[8]);
    float a3 = fmaxf(fmaxf(s0[9], s0[10]), s0[11]);
    float a4 = fmaxf(fmaxf(s0[12], s0[13]), s0[14]);
    float mx = fmaxf(fmaxf(fmaxf(a0, a1), a2), fmaxf(fmaxf(a3, a4), s0[15]));
    mx = fmaxf(mx, __shfl_xor(mx, 32));
    // ---- defer-max: rescale only when max grew by > 8 (log2 domain);
    //      scale redistributed via shfl (row f(r,hi) held by lane q31==row)
    if (__any(mx > m_i + 8.f)){
      float mn = fmaxf(m_i, mx);
      float sc_ = __builtin_exp2f(m_i - mn);
      #pragma unroll
      for (int r = 0; r < 16; ++r){
        float s = __shfl(sc_, (r & 3) + 8 * (r >> 2) + 4 * hi);
        o0[r] *= s; o1[r] *= s; ol[r] *= s;
      }
      m_i = mn;
    }
    // ---- p = exp2(s - m) in place
    #pragma unroll
    for (int r = 0; r < 16; ++r) s0[r] = __builtin_exp2f(s0[r] - m_i);
    // ---- PV + row-sum: A = in-lane pack of own p regs; V^T from LDS;
    //      l accumulated by all-ones MFMA on the matrix pipe
    union { i4 i; bf8 h; } pa;
    __builtin_amdgcn_s_setprio(1);
    #pragma unroll
    for (int ks = 0; ks < 2; ++ks){
      const int off = ks * 8;
      pa.i = (i4){ cvtpk(s0[off], s0[off+1]), cvtpk(s0[off+2], s0[off+3]),
                   cvtpk(s0[off+4], s0[off+5]), cvtpk(s0[off+6], s0[off+7]) };
      bf8 v0 = *(const bf8*)&Vs[cur][q31]     [((2 * ks + hi) ^ ((q31 >> 2) & 3)) * 8];
      bf8 v1 = *(const bf8*)&Vs[cur][32 + q31][((2 * ks + hi) ^ ((q31 >> 2) & 3)) * 8];
      o0 = __builtin_amdgcn_mfma_f32_32x32x16_bf16(pa.h, v0, o0, 0, 0, 0);
      o1 = __builtin_amdgcn_mfma_f32_32x32x16_bf16(pa.h, v1, o1, 0, 0, 0);
      ol = __builtin_amdgcn_mfma_f32_32x32x16_bf16(pa.h, ones, ol, 0, 0, 0);
    }
    __builtin_amdgcn_s_setprio(0);
  }

  // ---- epilogue: per-register exact 1/l, store Y (bf16); no LDS, no cross-lane
  #pragma unroll
  for (int r = 0; r < 16; ++r){
    int qrow = q0 + (r & 3) + 8 * (r >> 2) + 4 * hi;
    float inv = 1.0f / ol[r];
    size_t base = ((size_t)b_ * T + qrow) * CEMB + h * HD;
    Yb[base + q31]      = f2bf(o0[r] * inv);
    Yb[base + 32 + q31] = f2bf(o1[r] * inv);
  }
}

// ---- Output projection (m97 structure), fp32 out ----
__global__ __launch_bounds__(256) void gemm_out(const unsigned short* __restrict__ A,
                                                const unsigned short* __restrict__ Wb,
                                                const float* __restrict__ bias,
                                                float* __restrict__ out){
  __shared__ __align__(16) unsigned short As[128][64];
  __shared__ __align__(16) unsigned short Bs[128][64];
  int Lid = blockIdx.x + gridDim.x * blockIdx.y;      // 6*64 = 384 = 8*48
  int L2 = (Lid & 7) * 48 + (Lid >> 3);
  const int m0 = (L2 / 6) * 128, n0 = (L2 % 6) * 128;
  const int tid = threadIdx.x, w = tid >> 6, lane = tid & 63;
  const int wm = (w >> 1) * 64, wn = (w & 1) * 64;
  const int l15 = lane & 15, g = lane >> 4;
  const int srow = lane >> 3;
  const int scol = ((lane & 7) ^ srow) * 8;
  f4 acc[4][4] = {};
  for (int k0 = 0; k0 < CEMB; k0 += 64){
    #pragma unroll
    for (int i = 0; i < 4; ++i){
      int rb = i * 32 + w * 8;
      gload16(&A [(size_t)(m0 + rb + srow) * CEMB + k0 + scol], &As[rb][0]);
      gload16(&Wb[(size_t)(n0 + rb + srow) * CEMB + k0 + scol], &Bs[rb][0]);
    }
    __syncthreads();
    #pragma unroll
    for (int kq = 0; kq < 2; ++kq){
      bf8 a[4], b[4];
      #pragma unroll
      for (int i = 0; i < 4; ++i){
        int row = wm + i * 16 + l15;
        a[i] = *(const bf8*)&As[row][(((kq << 2) + g) ^ (row & 7)) * 8];
      }
      #pragma unroll
      for (int j = 0; j < 4; ++j){
        int row = wn + j * 16 + l15;
        b[j] = *(const bf8*)&Bs[row][(((kq << 2) + g) ^ (row & 7)) * 8];
      }
      #pragma unroll
      for (int i = 0; i < 4; ++i)
        #pragma unroll
        for (int j = 0; j < 4; ++j)
          acc[i][j] = __builtin_amdgcn_mfma_f32_16x16x32_bf16(a[i], b[j], acc[i][j], 0, 0, 0);
    }
    __syncthreads();
  }
  #pragma unroll
  for (int j = 0; j < 4; ++j){
    int ncol = n0 + wn + j * 16 + l15;
    float bv = bias[ncol];
    #pragma unroll
    for (int i = 0; i < 4; ++i){
      #pragma unroll
      for (int r = 0; r < 4; ++r){
        int m = m0 + wm + i * 16 + g * 4 + r;
        out[(size_t)m * CEMB + ncol] = acc[i][j][r] + bv;
      }
    }
  }
}

extern "C" void kernel_launch(void* const* d_in, const int* in_sizes, int n_in,
                              void* d_out, int out_size, void* d_ws, size_t ws_size,
                              hipStream_t stream){
  const float* x      = (const float*)d_in[0];
  const float* W_attn = (const float*)d_in[1];
  const float* b_attn = (const float*)d_in[2];
  const float* W_o    = (const float*)d_in[3];
  const float* b_o    = (const float*)d_in[4];
  float* out = (float*)d_out;

  char* ws = (char*)d_ws;
  const size_t SZ_T  = (size_t)48 * T * HD * 2;   // 12.58 MB (== X size)
  const size_t SZ_WA = (size_t)N1 * K1 * 2;
  const size_t SZ_WO = (size_t)CEMB * CEMB * 2;
  unsigned short* Xb = (unsigned short*)(ws);
  unsigned short* Wa = (unsigned short*)(ws + SZ_T);
  unsigned short* Wo = (unsigned short*)(ws + SZ_T + SZ_WA);
  unsigned short* Qb = (unsigned short*)(ws + SZ_T + SZ_WA + SZ_WO);
  unsigned short* Kb = (unsigned short*)(ws + SZ_T + SZ_WA + SZ_WO + SZ_T);
  unsigned short* Vt = (unsigned short*)(ws + SZ_T + SZ_WA + SZ_WO + 2 * SZ_T);
  unsigned short* Yb = Xb;   // Xb dead after gemm_qkv; attn writes Y here

  const int n4tot = (M1 * K1 + N1 * K1 + CEMB * CEMB) / 4;
  cvt_all<<<(n4tot + 255) / 256, 256, 0, stream>>>(x, W_attn, W_o, Xb, Wa, Wo);

  gemm_qkv<<<dim3(N1 / 128, M1 / 128), 256, 0, stream>>>(Xb, Wa, b_attn, Qb, Kb, Vt);
  attn<<<dim3(48, 64), 64, 0, stream>>>(Qb, Kb, Vt, Yb);
  gemm_out<<<dim3(CEMB / 128, M1 / 128), 256, 0, stream>>>(Yb, Wo, b_o, out);
}